// Round 4
// baseline (27.187 us; speedup 1.0000x reference)
//
#include <hip/hip_runtime.h>

#define BATCH 4096
#define IN_DIM 512
#define OUT_DIM 512
#define NK 4
#define SX (IN_DIM + NK)   // 516 floats per x row
#define BM 64
#define BN 32
#define BK 64

typedef short bf16x8 __attribute__((ext_vector_type(8)));
typedef float f32x4 __attribute__((ext_vector_type(4)));

__device__ __forceinline__ unsigned short f2bf(float f) {
    unsigned int u = __float_as_uint(f);
    u = u + 0x7FFFu + ((u >> 16) & 1u);   // round-to-nearest-even
    return (unsigned short)(u >> 16);
}

__device__ __forceinline__ void gload_lds16(const void* g, void* l) {
    __builtin_amdgcn_global_load_lds(
        (const __attribute__((address_space(1))) void*)g,
        (__attribute__((address_space(3))) void*)l, 16, 0, 0);
}

// ---------------- kernel 1: fp32 -> bf16 pre-pass ----------------
__global__ __launch_bounds__(256) void convert_kernel(
    const float* __restrict__ x, const float* __restrict__ w,
    unsigned short* __restrict__ wb, unsigned short* __restrict__ fb)
{
    const int WCH = NK * OUT_DIM * IN_DIM / 4;   // 262144 float4 chunks of W
    int g = blockIdx.x * 256 + threadIdx.x;
    if (g < WCH) {
        const float4 v = reinterpret_cast<const float4*>(w)[g];
        unsigned short h[4] = {f2bf(v.x), f2bf(v.y), f2bf(v.z), f2bf(v.w)};
        *reinterpret_cast<uint2*>(&wb[g * 4]) = *reinterpret_cast<const uint2*>(h);
    } else {
        int idx = g - WCH;                        // feat chunks: 4096*128
        int row = idx >> 7;
        int c   = (idx & 127) * 4;
        const float4 v = *reinterpret_cast<const float4*>(&x[(size_t)row * SX + c]);
        unsigned short h[4] = {f2bf(v.x), f2bf(v.y), f2bf(v.z), f2bf(v.w)};
        *reinterpret_cast<uint2*>(&fb[row * IN_DIM + c]) = *reinterpret_cast<const uint2*>(h);
    }
}

// ---------------- kernel 2: 128-thread (2-wave) bf16 MFMA GEMM ----------------
// Block tile: 64 rows x 32 cols x 4 knots. Wave-tile 32x32 (M_r=2,N_r=2) per knot.
// Single-buffered 24KB LDS -> 4+ independent blocks/CU for implicit overlap.
__global__ __launch_bounds__(128) void mpl_gemm(
    const unsigned short* __restrict__ fb,   // (4096,512) bf16
    const unsigned short* __restrict__ wb,   // (4,512,512) bf16
    const float* __restrict__ x,             // (4096,516) fp32 (for p)
    const float* __restrict__ bias,          // (4,512)
    float* __restrict__ out)                 // (4096,512)
{
    __shared__ unsigned short As[BM * BK];            // 8 KB, swizzled content
    __shared__ unsigned short Bs[NK * BN * BK];       // 16 KB, swizzled content

    const int tid  = threadIdx.x;          // 0..127
    const int lane = tid & 63;
    const int wid  = tid >> 6;             // 0..1
    const int wr   = wid * 32;             // wave row offset
    const int R0   = blockIdx.x * BM;
    const int C0   = blockIdx.y * BN;

    f32x4 acc[NK][2][2] = {};
    const int cl = lane & 15;
    const int kb = (lane >> 4) * 8;

    for (int kt = 0; kt < IN_DIM / BK; ++kt) {
        const int k0 = kt * BK;
        __syncthreads();                    // WAR: everyone done reading prev tile
        // ---- stage A: 512 chunks of 16B; dest linear, source chunk-permuted ----
        #pragma unroll
        for (int j = 0; j < 4; ++j) {
            int ch  = j * 128 + tid;        // dest = uniform + lane*16
            int row = ch >> 3;
            int c   = ch & 7;
            gload_lds16(fb + (size_t)(R0 + row) * IN_DIM + k0 + ((c ^ (row & 7)) << 3),
                        &As[ch * 8]);
        }
        // ---- stage B: 1024 chunks (4 knots x 32 rows x 8) ----
        #pragma unroll
        for (int j = 0; j < 8; ++j) {
            int ch  = j * 128 + tid;
            int kn  = ch >> 8;
            int rem = ch & 255;
            int row = rem >> 3;
            int c   = rem & 7;
            gload_lds16(wb + (size_t)kn * OUT_DIM * IN_DIM + (size_t)(C0 + row) * IN_DIM
                           + k0 + ((c ^ (row & 7)) << 3),
                        &Bs[kn * BN * BK + (rem << 3)]);
        }
        __syncthreads();                    // tile staged (compiler drains vmcnt here)
        // ---- MFMA ----
        __builtin_amdgcn_s_setprio(1);
        #pragma unroll
        for (int kk = 0; kk < BK; kk += 32) {
            bf16x8 af[2];
            #pragma unroll
            for (int m = 0; m < 2; ++m) {
                int row  = wr + m * 16 + cl;
                int boff = (row * 128 + (kk + kb) * 2) ^ ((row & 7) << 4);
                af[m] = *reinterpret_cast<const bf16x8*>(
                    reinterpret_cast<const char*>(As) + boff);
            }
            #pragma unroll
            for (int kn = 0; kn < NK; ++kn) {
                bf16x8 bfr[2];
                #pragma unroll
                for (int n = 0; n < 2; ++n) {
                    int row  = n * 16 + cl;
                    int boff = (row * 128 + (kk + kb) * 2) ^ ((row & 7) << 4);
                    bfr[n] = *reinterpret_cast<const bf16x8*>(
                        reinterpret_cast<const char*>(Bs) + kn * (BN * BK * 2) + boff);
                }
                #pragma unroll
                for (int m = 0; m < 2; ++m)
                    #pragma unroll
                    for (int n = 0; n < 2; ++n)
                        acc[kn][m][n] = __builtin_amdgcn_mfma_f32_16x16x32_bf16(
                            af[m], bfr[n], acc[kn][m][n], 0, 0, 0);
            }
        }
        __builtin_amdgcn_s_setprio(0);
    }

    // ---- epilogue: res = sum_k p[b,k]*(acc_k + bias_k[o]); elu ----
    const int rl = (lane >> 4) * 4;
    float bcol[2][NK];
    #pragma unroll
    for (int n = 0; n < 2; ++n)
        #pragma unroll
        for (int k = 0; k < NK; ++k)
            bcol[n][k] = bias[k * OUT_DIM + C0 + n * 16 + cl];

    #pragma unroll
    for (int m = 0; m < 2; ++m) {
        #pragma unroll
        for (int r = 0; r < 4; ++r) {
            const int row = R0 + wr + m * 16 + rl + r;
            const float4 p = *reinterpret_cast<const float4*>(&x[(size_t)row * SX + IN_DIM]);
            const float pk[4] = {p.x, p.y, p.z, p.w};
            #pragma unroll
            for (int n = 0; n < 2; ++n) {
                float v = 0.f;
                #pragma unroll
                for (int k = 0; k < NK; ++k)
                    v += pk[k] * (acc[k][m][n][r] + bcol[n][k]);
                v = (v > 0.f) ? v : expm1f(v);
                out[(size_t)row * OUT_DIM + C0 + n * 16 + cl] = v;
            }
        }
    }
}

// ---------------- fallback (round-1 kernel) if ws too small ----------------
#define LDT 72
__global__ __launch_bounds__(256) void mpl_kernel_fb(
    const float* __restrict__ x, const float* __restrict__ w,
    const float* __restrict__ bias, float* __restrict__ out)
{
    __shared__ unsigned short Asf[BM][LDT];
    __shared__ unsigned short Bsf[NK][64][LDT];
    const int tid = threadIdx.x, lane = tid & 63, wid = tid >> 6;
    const int wr = (wid >> 1) * 32, wc = (wid & 1) * 32;
    const int R0 = blockIdx.x * BM, C0 = blockIdx.y * 64;
    f32x4 acc[NK][2][2] = {};
    const int cl = lane & 15, kb = (lane >> 4) * 8;
    for (int kt = 0; kt < IN_DIM / BK; ++kt) {
        const int k0 = kt * BK;
        __syncthreads();
        #pragma unroll
        for (int j = 0; j < 4; ++j) {
            int f = tid + 256 * j, row = f >> 4, c4 = (f & 15) * 4;
            const float4 v = *reinterpret_cast<const float4*>(&x[(size_t)(R0 + row) * SX + k0 + c4]);
            unsigned short h[4] = {f2bf(v.x), f2bf(v.y), f2bf(v.z), f2bf(v.w)};
            *reinterpret_cast<uint2*>(&Asf[row][c4]) = *reinterpret_cast<const uint2*>(h);
        }
        #pragma unroll
        for (int kn = 0; kn < NK; ++kn)
            #pragma unroll
            for (int j = 0; j < 4; ++j) {
                int f = tid + 256 * j, row = f >> 4, c4 = (f & 15) * 4;
                const float4 v = *reinterpret_cast<const float4*>(
                    &w[(size_t)kn * OUT_DIM * IN_DIM + (size_t)(C0 + row) * IN_DIM + k0 + c4]);
                unsigned short h[4] = {f2bf(v.x), f2bf(v.y), f2bf(v.z), f2bf(v.w)};
                *reinterpret_cast<uint2*>(&Bsf[kn][row][c4]) = *reinterpret_cast<const uint2*>(h);
            }
        __syncthreads();
        #pragma unroll
        for (int kk = 0; kk < BK; kk += 32) {
            bf16x8 af[2];
            #pragma unroll
            for (int m = 0; m < 2; ++m)
                af[m] = *reinterpret_cast<const bf16x8*>(&Asf[wr + m * 16 + cl][kk + kb]);
            #pragma unroll
            for (int kn = 0; kn < NK; ++kn) {
                bf16x8 bfr[2];
                #pragma unroll
                for (int n = 0; n < 2; ++n)
                    bfr[n] = *reinterpret_cast<const bf16x8*>(&Bsf[kn][wc + n * 16 + cl][kk + kb]);
                #pragma unroll
                for (int m = 0; m < 2; ++m)
                    #pragma unroll
                    for (int n = 0; n < 2; ++n)
                        acc[kn][m][n] = __builtin_amdgcn_mfma_f32_16x16x32_bf16(
                            af[m], bfr[n], acc[kn][m][n], 0, 0, 0);
            }
        }
    }
    const int rl = (lane >> 4) * 4;
    float bcol[2][NK];
    #pragma unroll
    for (int n = 0; n < 2; ++n)
        #pragma unroll
        for (int k = 0; k < NK; ++k)
            bcol[n][k] = bias[k * OUT_DIM + C0 + wc + n * 16 + cl];
    #pragma unroll
    for (int m = 0; m < 2; ++m)
        #pragma unroll
        for (int r = 0; r < 4; ++r) {
            const int row = R0 + wr + m * 16 + rl + r;
            const float4 p = *reinterpret_cast<const float4*>(&x[(size_t)row * SX + IN_DIM]);
            const float pk[4] = {p.x, p.y, p.z, p.w};
            #pragma unroll
            for (int n = 0; n < 2; ++n) {
                float v = 0.f;
                #pragma unroll
                for (int k = 0; k < NK; ++k)
                    v += pk[k] * (acc[k][m][n][r] + bcol[n][k]);
                v = (v > 0.f) ? v : expm1f(v);
                out[(size_t)row * OUT_DIM + C0 + wc + n * 16 + cl] = v;
            }
        }
}

extern "C" void kernel_launch(void* const* d_in, const int* in_sizes, int n_in,
                              void* d_out, int out_size, void* d_ws, size_t ws_size,
                              hipStream_t stream) {
    const float* x    = (const float*)d_in[0];
    const float* w    = (const float*)d_in[1];
    const float* bias = (const float*)d_in[2];
    float* out        = (float*)d_out;

    const size_t wb_bytes = (size_t)NK * OUT_DIM * IN_DIM * 2;   // 2 MB
    const size_t fb_bytes = (size_t)BATCH * IN_DIM * 2;          // 4 MB

    if (ws_size < wb_bytes + fb_bytes) {
        dim3 grid(BATCH / BM, OUT_DIM / 64);
        mpl_kernel_fb<<<grid, dim3(256), 0, stream>>>(x, w, bias, out);
        return;
    }

    unsigned short* wb = (unsigned short*)d_ws;
    unsigned short* fb = (unsigned short*)((char*)d_ws + wb_bytes);

    const int total_chunks = NK * OUT_DIM * IN_DIM / 4 + BATCH * IN_DIM / 4;  // 786432
    convert_kernel<<<dim3(total_chunks / 256), dim3(256), 0, stream>>>(x, w, wb, fb);

    dim3 grid(BATCH / BM, OUT_DIM / BN);
    mpl_gemm<<<grid, dim3(128), 0, stream>>>(fb, wb, x, bias, out);
}

// Round 5
// 26.564 us; speedup vs baseline: 1.0234x; 1.0234x over previous
//
#include <hip/hip_runtime.h>

#define BATCH 4096
#define IN_DIM 512
#define OUT_DIM 512
#define NK 4
#define SX (IN_DIM + NK)   // 516 floats per x row
#define BM 64
#define BN 64
#define BK 64
#define KT (IN_DIM / BK)   // 8 K-tiles

typedef short bf16x8 __attribute__((ext_vector_type(8)));
typedef float f32x4 __attribute__((ext_vector_type(4)));

__device__ __forceinline__ unsigned short f2bf(float f) {
    unsigned int u = __float_as_uint(f);
    u = u + 0x7FFFu + ((u >> 16) & 1u);   // round-to-nearest-even
    return (unsigned short)(u >> 16);
}

__device__ __forceinline__ void gload_lds16(const void* g, void* l) {
    __builtin_amdgcn_global_load_lds(
        (const __attribute__((address_space(1))) void*)g,
        (__attribute__((address_space(3))) void*)l, 16, 0, 0);
}

// ---------------- kernel 1: fp32 -> bf16 pre-pass ----------------
__global__ __launch_bounds__(256) void convert_kernel(
    const float* __restrict__ x, const float* __restrict__ w,
    unsigned short* __restrict__ wb, unsigned short* __restrict__ fb)
{
    const int WCH = NK * OUT_DIM * IN_DIM / 4;   // 262144 float4 chunks of W
    int g = blockIdx.x * 256 + threadIdx.x;
    if (g < WCH) {
        const float4 v = reinterpret_cast<const float4*>(w)[g];
        unsigned short h[4] = {f2bf(v.x), f2bf(v.y), f2bf(v.z), f2bf(v.w)};
        *reinterpret_cast<uint2*>(&wb[g * 4]) = *reinterpret_cast<const uint2*>(h);
    } else {
        int idx = g - WCH;                        // feat chunks: 4096*128
        int row = idx >> 7;
        int c   = (idx & 127) * 4;
        const float4 v = *reinterpret_cast<const float4*>(&x[(size_t)row * SX + c]);
        unsigned short h[4] = {f2bf(v.x), f2bf(v.y), f2bf(v.z), f2bf(v.w)};
        *reinterpret_cast<uint2*>(&fb[row * IN_DIM + c]) = *reinterpret_cast<const uint2*>(h);
    }
}

// ------- kernel 2: counted-vmcnt 2-deep pipelined bf16 MFMA GEMM (T3+T4) -------
// 10 global_load_lds per wave per tile; vmcnt(10) waits for the OLDER tile only.
__global__ __launch_bounds__(256) void mpl_gemm(
    const unsigned short* __restrict__ fb,   // (4096,512) bf16
    const unsigned short* __restrict__ wb,   // (4,512,512) bf16
    const float* __restrict__ x,             // (4096,516) fp32 (for p)
    const float* __restrict__ bias,          // (4,512)
    float* __restrict__ out)                 // (4096,512)
{
    __shared__ unsigned short As[2 * BM * BK];        // 2 x 8 KB
    __shared__ unsigned short Bs[2 * NK * BN * BK];   // 2 x 32 KB

    const int tid  = threadIdx.x;
    const int lane = tid & 63;
    const int wid  = tid >> 6;
    const int wr   = (wid >> 1) * 32;
    const int wc   = (wid & 1) * 32;
    const int R0   = blockIdx.x * BM;
    const int C0   = blockIdx.y * BN;

    f32x4 acc[NK][2][2] = {};
    const int cl = lane & 15;
    const int kb = (lane >> 4) * 8;

    // ---- stage: issue 10 global_load_lds (2 A + 8 B per thread) for tile k0 ----
    auto stage = [&](int b, int k0) {
        #pragma unroll
        for (int j = 0; j < 2; ++j) {
            int ch  = j * 256 + tid;                 // dest = uniform + lane*16
            int row = ch >> 3;
            int c   = ch & 7;
            gload_lds16(fb + (size_t)(R0 + row) * IN_DIM + k0 + ((c ^ (row & 7)) << 3),
                        &As[b * BM * BK + ch * 8]);
        }
        #pragma unroll
        for (int j = 0; j < 8; ++j) {
            int ch  = j * 256 + tid;
            int kn  = ch >> 9;
            int rem = ch & 511;
            int row = rem >> 3;
            int c   = rem & 7;
            gload_lds16(wb + (size_t)kn * OUT_DIM * IN_DIM + (size_t)(C0 + row) * IN_DIM
                           + k0 + ((c ^ (row & 7)) << 3),
                        &Bs[b * NK * BN * BK + ch * 8]);
        }
    };

    auto compute = [&](int b) {
        const char* Ab = reinterpret_cast<const char*>(As) + b * BM * BK * 2;
        const char* Bb = reinterpret_cast<const char*>(Bs) + b * NK * BN * BK * 2;
        #pragma unroll
        for (int kk = 0; kk < BK; kk += 32) {
            bf16x8 af[2];
            #pragma unroll
            for (int m = 0; m < 2; ++m) {
                int row  = wr + m * 16 + cl;
                int boff = (row * 128 + (kk + kb) * 2) ^ ((row & 7) << 4);
                af[m] = *reinterpret_cast<const bf16x8*>(Ab + boff);
            }
            #pragma unroll
            for (int kn = 0; kn < NK; ++kn) {
                bf16x8 bfr[2];
                #pragma unroll
                for (int n = 0; n < 2; ++n) {
                    int row  = wc + n * 16 + cl;
                    int boff = (row * 128 + (kk + kb) * 2) ^ ((row & 7) << 4);
                    bfr[n] = *reinterpret_cast<const bf16x8*>(Bb + kn * 8192 + boff);
                }
                __builtin_amdgcn_s_setprio(1);
                #pragma unroll
                for (int m = 0; m < 2; ++m)
                    #pragma unroll
                    for (int n = 0; n < 2; ++n)
                        acc[kn][m][n] = __builtin_amdgcn_mfma_f32_16x16x32_bf16(
                            af[m], bfr[n], acc[kn][m][n], 0, 0, 0);
                __builtin_amdgcn_s_setprio(0);
            }
        }
    };

    // ---- prologue: 2-deep prefetch (20 loads in flight per wave) ----
    stage(0, 0);
    stage(1, BK);
    // ---- K-loop: counted vmcnt, raw barriers, never drain to 0 mid-loop ----
    #pragma unroll
    for (int kt = 0; kt < KT; ++kt) {
        const int cur = kt & 1;
        if (kt < KT - 1) asm volatile("s_waitcnt vmcnt(10)" ::: "memory");
        else             asm volatile("s_waitcnt vmcnt(0)"  ::: "memory");
        __builtin_amdgcn_s_barrier();     // all waves' tile-kt loads now visible
        compute(cur);
        __builtin_amdgcn_s_barrier();     // WAR: everyone done reading buffer cur
        if (kt < KT - 2) stage(cur, (kt + 2) * BK);
    }

    // ---- epilogue: res = sum_k p[b,k]*(acc_k + bias_k[o]); elu ----
    const int rl = (lane >> 4) * 4;
    float bcol[2][NK];
    #pragma unroll
    for (int n = 0; n < 2; ++n)
        #pragma unroll
        for (int k = 0; k < NK; ++k)
            bcol[n][k] = bias[k * OUT_DIM + C0 + wc + n * 16 + cl];

    #pragma unroll
    for (int m = 0; m < 2; ++m) {
        #pragma unroll
        for (int r = 0; r < 4; ++r) {
            const int row = R0 + wr + m * 16 + rl + r;
            const float4 p = *reinterpret_cast<const float4*>(&x[(size_t)row * SX + IN_DIM]);
            const float pk[4] = {p.x, p.y, p.z, p.w};
            #pragma unroll
            for (int n = 0; n < 2; ++n) {
                float v = 0.f;
                #pragma unroll
                for (int k = 0; k < NK; ++k)
                    v += pk[k] * (acc[k][m][n][r] + bcol[n][k]);
                v = (v > 0.f) ? v : expm1f(v);
                out[(size_t)row * OUT_DIM + C0 + wc + n * 16 + cl] = v;
            }
        }
    }
}

// ---------------- fallback (round-1 kernel) if ws too small ----------------
#define LDT 72
__global__ __launch_bounds__(256) void mpl_kernel_fb(
    const float* __restrict__ x, const float* __restrict__ w,
    const float* __restrict__ bias, float* __restrict__ out)
{
    __shared__ unsigned short Asf[BM][LDT];
    __shared__ unsigned short Bsf[NK][64][LDT];
    const int tid = threadIdx.x, lane = tid & 63, wid = tid >> 6;
    const int wr = (wid >> 1) * 32, wc = (wid & 1) * 32;
    const int R0 = blockIdx.x * BM, C0 = blockIdx.y * 64;
    f32x4 acc[NK][2][2] = {};
    const int cl = lane & 15, kb = (lane >> 4) * 8;
    for (int kt = 0; kt < KT; ++kt) {
        const int k0 = kt * BK;
        __syncthreads();
        #pragma unroll
        for (int j = 0; j < 4; ++j) {
            int f = tid + 256 * j, row = f >> 4, c4 = (f & 15) * 4;
            const float4 v = *reinterpret_cast<const float4*>(&x[(size_t)(R0 + row) * SX + k0 + c4]);
            unsigned short h[4] = {f2bf(v.x), f2bf(v.y), f2bf(v.z), f2bf(v.w)};
            *reinterpret_cast<uint2*>(&Asf[row][c4]) = *reinterpret_cast<const uint2*>(h);
        }
        #pragma unroll
        for (int kn = 0; kn < NK; ++kn)
            #pragma unroll
            for (int j = 0; j < 4; ++j) {
                int f = tid + 256 * j, row = f >> 4, c4 = (f & 15) * 4;
                const float4 v = *reinterpret_cast<const float4*>(
                    &w[(size_t)kn * OUT_DIM * IN_DIM + (size_t)(C0 + row) * IN_DIM + k0 + c4]);
                unsigned short h[4] = {f2bf(v.x), f2bf(v.y), f2bf(v.z), f2bf(v.w)};
                *reinterpret_cast<uint2*>(&Bsf[kn][row][c4]) = *reinterpret_cast<const uint2*>(h);
            }
        __syncthreads();
        #pragma unroll
        for (int kk = 0; kk < BK; kk += 32) {
            bf16x8 af[2];
            #pragma unroll
            for (int m = 0; m < 2; ++m)
                af[m] = *reinterpret_cast<const bf16x8*>(&Asf[wr + m * 16 + cl][kk + kb]);
            #pragma unroll
            for (int kn = 0; kn < NK; ++kn) {
                bf16x8 bfr[2];
                #pragma unroll
                for (int n = 0; n < 2; ++n)
                    bfr[n] = *reinterpret_cast<const bf16x8*>(&Bsf[kn][wc + n * 16 + cl][kk + kb]);
                #pragma unroll
                for (int m = 0; m < 2; ++m)
                    #pragma unroll
                    for (int n = 0; n < 2; ++n)
                        acc[kn][m][n] = __builtin_amdgcn_mfma_f32_16x16x32_bf16(
                            af[m], bfr[n], acc[kn][m][n], 0, 0, 0);
            }
        }
    }
    const int rl = (lane >> 4) * 4;
    float bcol[2][NK];
    #pragma unroll
    for (int n = 0; n < 2; ++n)
        #pragma unroll
        for (int k = 0; k < NK; ++k)
            bcol[n][k] = bias[k * OUT_DIM + C0 + wc + n * 16 + cl];
    #pragma unroll
    for (int m = 0; m < 2; ++m)
        #pragma unroll
        for (int r = 0; r < 4; ++r) {
            const int row = R0 + wr + m * 16 + rl + r;
            const float4 p = *reinterpret_cast<const float4*>(&x[(size_t)row * SX + IN_DIM]);
            const float pk[4] = {p.x, p.y, p.z, p.w};
            #pragma unroll
            for (int n = 0; n < 2; ++n) {
                float v = 0.f;
                #pragma unroll
                for (int k = 0; k < NK; ++k)
                    v += pk[k] * (acc[k][m][n][r] + bcol[n][k]);
                v = (v > 0.f) ? v : expm1f(v);
                out[(size_t)row * OUT_DIM + C0 + wc + n * 16 + cl] = v;
            }
        }
}

extern "C" void kernel_launch(void* const* d_in, const int* in_sizes, int n_in,
                              void* d_out, int out_size, void* d_ws, size_t ws_size,
                              hipStream_t stream) {
    const float* x    = (const float*)d_in[0];
    const float* w    = (const float*)d_in[1];
    const float* bias = (const float*)d_in[2];
    float* out        = (float*)d_out;

    const size_t wb_bytes = (size_t)NK * OUT_DIM * IN_DIM * 2;   // 2 MB
    const size_t fb_bytes = (size_t)BATCH * IN_DIM * 2;          // 4 MB

    if (ws_size < wb_bytes + fb_bytes) {
        dim3 grid(BATCH / BM, OUT_DIM / 64);
        mpl_kernel_fb<<<grid, dim3(256), 0, stream>>>(x, w, bias, out);
        return;
    }

    unsigned short* wb = (unsigned short*)d_ws;
    unsigned short* fb = (unsigned short*)((char*)d_ws + wb_bytes);

    const int total_chunks = NK * OUT_DIM * IN_DIM / 4 + BATCH * IN_DIM / 4;  // 786432
    convert_kernel<<<dim3(total_chunks / 256), dim3(256), 0, stream>>>(x, w, wb, fb);

    dim3 grid(BATCH / BM, OUT_DIM / BN);
    mpl_gemm<<<grid, dim3(256), 0, stream>>>(fb, wb, x, bias, out);
}